// Round 5
// baseline (692.845 us; speedup 1.0000x reference)
//
#include <hip/hip_runtime.h>

#define NN 100000
#define NE 1600000

typedef __bf16 bf16x2 __attribute__((ext_vector_type(2)));
typedef __bf16 bf16x4 __attribute__((ext_vector_type(4)));
typedef __bf16 bf16x8 __attribute__((ext_vector_type(8)));
typedef float f32x4 __attribute__((ext_vector_type(4)));

constexpr int SCAN_BLOCKS = (NN + 255) / 256;  // 391

// ---------------- graph preprocessing ----------------

__global__ __launch_bounds__(256) void k_count(const int* __restrict__ dst, int* __restrict__ counts) {
  int e = blockIdx.x * 256 + threadIdx.x;
  if (e < NE) atomicAdd(&counts[dst[e]], 1);
}

__global__ __launch_bounds__(256) void k_dis(const int* __restrict__ counts, float* __restrict__ dis) {
  int i = blockIdx.x * 256 + threadIdx.x;
  if (i < NN) dis[i] = rsqrtf((float)(counts[i] + 1));  // +1 self-loop; deg >= 1 always
}

__global__ __launch_bounds__(256) void k_scan_block(const int* __restrict__ counts, int* __restrict__ row_ptr,
                                                    int* __restrict__ bsums) {
  __shared__ int s[256];
  int tid = threadIdx.x;
  int i = blockIdx.x * 256 + tid;
  int v = (i < NN) ? counts[i] : 0;
  s[tid] = v;
  __syncthreads();
  for (int off = 1; off < 256; off <<= 1) {
    int t = (tid >= off) ? s[tid - off] : 0;
    __syncthreads();
    s[tid] += t;
    __syncthreads();
  }
  if (i < NN) row_ptr[i + 1] = s[tid];
  if (tid == 255) bsums[blockIdx.x] = s[255];
}

__global__ __launch_bounds__(512) void k_scan_bsums(int* __restrict__ bsums) {
  __shared__ int s[512];
  int tid = threadIdx.x;
  int v = (tid < SCAN_BLOCKS) ? bsums[tid] : 0;
  s[tid] = v;
  __syncthreads();
  for (int off = 1; off < 512; off <<= 1) {
    int t = (tid >= off) ? s[tid - off] : 0;
    __syncthreads();
    s[tid] += t;
    __syncthreads();
  }
  bsums[tid] = s[tid];
}

__global__ __launch_bounds__(256) void k_scan_add(int* __restrict__ row_ptr, const int* __restrict__ bsums) {
  int i = blockIdx.x * 256 + threadIdx.x;
  if (i < NN && blockIdx.x > 0) row_ptr[i + 1] += bsums[blockIdx.x - 1];
  if (i == 0) row_ptr[0] = 0;
}

__global__ __launch_bounds__(256) void k_fill(const int* __restrict__ src, const int* __restrict__ dst,
                                              const int* __restrict__ row_ptr, int* __restrict__ cursor,
                                              int* __restrict__ csr_src) {
  int e = blockIdx.x * 256 + threadIdx.x;
  if (e < NE) {
    int d = dst[e];
    int pos = atomicAdd(&cursor[d], 1);
    csr_src[row_ptr[d] + pos] = src[e];
  }
}

// ---------------- bf16 MFMA GEMM: tmp[m,n] = dis[m] * (xform(A[m,:]) @ W)[n] ----------------
// MODE 0: A fp32 [*,128], no transform (layer 1: A = x).
// MODE 2: A bf16 [*,128] (agg from previous layer, lives in d_out); xform = relu(a + bias[k]).
// W fp32 [128,BN] row-major, bias fp32. tmp out bf16 [*,BN], scaled by dis[row].

template <int BN, int MODE>
__global__ __launch_bounds__(256) void k_gemm(const void* __restrict__ Av, const float* __restrict__ W,
                                              const float* __restrict__ bias, const float* __restrict__ dis,
                                              __bf16* __restrict__ out) {
  constexpr int LDK = 72;  // 64 + 8 pad: row stride 144 B -> bank rotation; 2-way conflict = free
  constexpr int NSH = (BN == 128) ? 7 : 6;
  constexpr int NT = BN / 32;  // 16-wide n-tiles per wave (wave tile = 64 x BN/2)
  __shared__ __bf16 lA[128 * LDK];
  __shared__ __bf16 lB[BN * LDK];

  const int tid = threadIdx.x;
  const int rowBase = blockIdx.x * 128;
  const int lane = tid & 63;
  const int wid = tid >> 6;
  const int wm = (wid & 1) * 64;
  const int wn = (wid >> 1) * (BN / 2);
  const int lm = lane & 15;
  const int kg = lane >> 4;

  f32x4 acc[4][NT] = {};

  for (int kb = 0; kb < 128; kb += 64) {
    if constexpr (MODE == 0) {
      const float* A = (const float*)Av;
      for (int i = tid; i < 128 * 16; i += 256) {
        int r = i >> 4;
        int c4 = (i & 15) * 4;
        int gr = rowBase + r;
        float4 v = make_float4(0.f, 0.f, 0.f, 0.f);
        if (gr < NN) v = *(const float4*)(A + (size_t)gr * 128 + kb + c4);
        bf16x4 bv = {(__bf16)v.x, (__bf16)v.y, (__bf16)v.z, (__bf16)v.w};
        *(bf16x4*)&lA[r * LDK + c4] = bv;
      }
    } else {
      const __bf16* A = (const __bf16*)Av;
      for (int i = tid; i < 128 * 8; i += 256) {
        int r = i >> 3;
        int c8 = (i & 7) * 8;
        int gr = rowBase + r;
        int gk = kb + c8;
        bf16x8 v = {};
        if (gr < NN) v = *(const bf16x8*)(A + (size_t)gr * 128 + gk);
        bf16x8 o;
#pragma unroll
        for (int j = 0; j < 8; ++j) o[j] = (__bf16)fmaxf((float)v[j] + bias[gk + j], 0.f);
        *(bf16x8*)&lA[r * LDK + c8] = o;
      }
    }
    // stage W tile transposed: lB[n][k] = W[kb+k][n]  (coalesced over n)
    for (int i = tid; i < 64 * BN; i += 256) {
      int n = i & (BN - 1);
      int k = i >> NSH;
      lB[n * LDK + k] = (__bf16)W[(size_t)(kb + k) * BN + n];
    }
    __syncthreads();
#pragma unroll
    for (int kk = 0; kk < 64; kk += 32) {
      bf16x8 af[4], bfr[NT];
#pragma unroll
      for (int tm = 0; tm < 4; ++tm)
        af[tm] = *(const bf16x8*)&lA[(wm + tm * 16 + lm) * LDK + kk + kg * 8];
#pragma unroll
      for (int tn = 0; tn < NT; ++tn)
        bfr[tn] = *(const bf16x8*)&lB[(wn + tn * 16 + lm) * LDK + kk + kg * 8];
#pragma unroll
      for (int tm = 0; tm < 4; ++tm)
#pragma unroll
        for (int tn = 0; tn < NT; ++tn)
          acc[tm][tn] = __builtin_amdgcn_mfma_f32_16x16x32_bf16(af[tm], bfr[tn], acc[tm][tn], 0, 0, 0);
    }
    __syncthreads();
  }

  // epilogue: C/D layout col=lane&15, row=(lane>>4)*4+reg; scale by dis[row], store bf16
#pragma unroll
  for (int tm = 0; tm < 4; ++tm) {
    int r0 = rowBase + wm + tm * 16 + kg * 4;
#pragma unroll
    for (int tn = 0; tn < NT; ++tn) {
      int c0 = wn + tn * 16 + lm;
#pragma unroll
      for (int r = 0; r < 4; ++r) {
        int gr = r0 + r;
        if (gr < NN) out[(size_t)gr * BN + c0] = (__bf16)(acc[tm][tn][r] * dis[gr]);
      }
    }
  }
}

// ---------------- pull aggregation: agg[n] = dis[n] * (sum_{s in in(n)} tmp[s] + tmp[n]) ----------------
// tmp rows already carry dis[src]. One wave per node; 64-edge batches broadcast via shfl.
// F=128: accumulate fp32, write bf16 (agg lives in d_out). F=64: write fp32 (final agg in d_out).

template <int F>
__global__ __launch_bounds__(256) void k_agg(const __bf16* __restrict__ tmp, const int* __restrict__ row_ptr,
                                             const int* __restrict__ csr_src, const float* __restrict__ dis,
                                             void* __restrict__ aggv) {
  int wid = (blockIdx.x * 256 + threadIdx.x) >> 6;
  int lane = threadIdx.x & 63;
  if (wid >= NN) return;
  int beg = row_ptr[wid];
  int end = row_ptr[wid + 1];
  if constexpr (F == 128) {
    bf16x2 sv = *(const bf16x2*)&tmp[(size_t)wid * 128 + lane * 2];
    float ax = (float)sv[0], ay = (float)sv[1];
    for (int base = beg; base < end; base += 64) {
      int cnt = min(64, end - base);
      int sidx = (base + lane < end) ? csr_src[base + lane] : 0;
      for (int j = 0; j < cnt; ++j) {
        int s = __shfl(sidx, j);
        bf16x2 v = *(const bf16x2*)&tmp[(size_t)s * 128 + lane * 2];
        ax += (float)v[0];
        ay += (float)v[1];
      }
    }
    float d = dis[wid];
    bf16x2 o = {(__bf16)(ax * d), (__bf16)(ay * d)};
    *(bf16x2*)((__bf16*)aggv + (size_t)wid * 128 + lane * 2) = o;
  } else {
    float a = (float)tmp[(size_t)wid * 64 + lane];
    for (int base = beg; base < end; base += 64) {
      int cnt = min(64, end - base);
      int sidx = (base + lane < end) ? csr_src[base + lane] : 0;
      for (int j = 0; j < cnt; ++j) {
        int s = __shfl(sidx, j);
        a += (float)tmp[(size_t)s * 64 + lane];
      }
    }
    ((float*)aggv)[(size_t)wid * 64 + lane] = a * dis[wid];
  }
}

// ---------------- final (in-place on d_out): relu(agg + b2) -> log_softmax, fp32 ----------------

__global__ __launch_bounds__(256) void k_final(float* __restrict__ buf, const float* __restrict__ b2) {
  int wid = (blockIdx.x * 256 + threadIdx.x) >> 6;
  int lane = threadIdx.x & 63;
  if (wid >= NN) return;
  float v = fmaxf(buf[(size_t)wid * 64 + lane] + b2[lane], 0.f);
  float m = v;
#pragma unroll
  for (int off = 32; off > 0; off >>= 1) m = fmaxf(m, __shfl_xor(m, off));
  float e = expf(v - m);
  float ss = e;
#pragma unroll
  for (int off = 32; off > 0; off >>= 1) ss += __shfl_xor(ss, off);
  buf[(size_t)wid * 64 + lane] = (v - m) - logf(ss);
}

// ---------------- launch ----------------

extern "C" void kernel_launch(void* const* d_in, const int* in_sizes, int n_in,
                              void* d_out, int out_size, void* d_ws, size_t ws_size,
                              hipStream_t stream) {
  const float* x  = (const float*)d_in[0];
  const int*   ei = (const int*)d_in[1];
  const float* W0 = (const float*)d_in[2];
  const float* b0 = (const float*)d_in[3];
  const float* W1 = (const float*)d_in[4];
  const float* b1 = (const float*)d_in[5];
  const float* W2 = (const float*)d_in[6];
  const float* b2 = (const float*)d_in[7];
  const int* esrc = ei;        // edge_index[0]
  const int* edst = ei + NE;   // edge_index[1]

  // Workspace budget (~33.6 MB total; previous 84 MB layout overran d_ws):
  char* p = (char*)d_ws;
  auto alloc = [&](size_t bytes) {
    char* q = p;
    p += (bytes + 255) & ~(size_t)255;
    return q;
  };
  int*    counts  = (int*)alloc((size_t)NN * 4);            // 0.4 MB
  float*  dis     = (float*)alloc((size_t)NN * 4);          // 0.4 MB
  int*    row_ptr = (int*)alloc((size_t)(NN + 1) * 4);      // 0.4 MB
  int*    cursor  = (int*)alloc((size_t)NN * 4);            // 0.4 MB
  int*    bsums   = (int*)alloc(512 * 4);                   // 2 KB
  int*    csr_src = (int*)alloc((size_t)NE * 4);            // 6.4 MB
  __bf16* tmp     = (__bf16*)alloc((size_t)NN * 128 * 2);   // 25.6 MB
  // agg lives in d_out (100000*64*4 B = 25.6 MB):
  //   layers 1-2: bf16 [NN,128] (exact fit), layer 3: fp32 [NN,64], k_final in-place.

  hipMemsetAsync(counts, 0, (size_t)NN * 4, stream);
  hipMemsetAsync(cursor, 0, (size_t)NN * 4, stream);

  int eblocks = (NE + 255) / 256;
  k_count<<<eblocks, 256, 0, stream>>>(edst, counts);
  k_dis<<<SCAN_BLOCKS, 256, 0, stream>>>(counts, dis);
  k_scan_block<<<SCAN_BLOCKS, 256, 0, stream>>>(counts, row_ptr, bsums);
  k_scan_bsums<<<1, 512, 0, stream>>>(bsums);
  k_scan_add<<<SCAN_BLOCKS, 256, 0, stream>>>(row_ptr, bsums);
  k_fill<<<eblocks, 256, 0, stream>>>(esrc, edst, row_ptr, cursor, csr_src);

  int gblocks = (NN + 127) / 128;
  int ablocks = (NN * 64 + 255) / 256;

  k_gemm<128, 0><<<gblocks, 256, 0, stream>>>(x, W0, nullptr, dis, tmp);
  k_agg<128><<<ablocks, 256, 0, stream>>>(tmp, row_ptr, csr_src, dis, d_out);  // agg1 bf16 in d_out

  k_gemm<128, 2><<<gblocks, 256, 0, stream>>>(d_out, W1, b0, dis, tmp);
  k_agg<128><<<ablocks, 256, 0, stream>>>(tmp, row_ptr, csr_src, dis, d_out);  // agg2 bf16 in d_out

  k_gemm<64, 2><<<gblocks, 256, 0, stream>>>(d_out, W2, b1, dis, tmp);
  k_agg<64><<<ablocks, 256, 0, stream>>>(tmp, row_ptr, csr_src, dis, d_out);   // agg3 fp32 in d_out

  k_final<<<ablocks, 256, 0, stream>>>((float*)d_out, b2);                     // in-place
}